// Round 5
// baseline (101.569 us; speedup 1.0000x reference)
//
#include <hip/hip_runtime.h>
#include <math.h>

#define INV_TWO_PI 0.15915494309189535f
#define PPB 4   // points per thread in the broadcast kernel (256 thr * 4 = 1024 pts)
#define FPB 8   // faces per block slice

// ---------------------------------------------------------------------------
// fast atan2: degree-15 odd minimax on [0,1] + quadrant fixup.
// Branch-cut semantics match numpy: atan2(+-0, neg) = +-pi, atan2(0,0)=0.
// ---------------------------------------------------------------------------
__device__ __forceinline__ float fast_atan2f(float y, float x) {
    const float PI   = 3.14159265358979f;
    const float PI_2 = 1.57079632679490f;
    float ax = fabsf(x), ay = fabsf(y);
    float mx = fmaxf(ax, ay), mn = fminf(ax, ay);
    float inv = __builtin_amdgcn_rcpf(mx);
    float t = (mx > 0.f) ? mn * inv : 0.f;   // guard 0/0
    float s = t * t;
    float r = -0.0040540580f;
    r = fmaf(r, s, 0.0218612288f);
    r = fmaf(r, s, -0.0559098861f);
    r = fmaf(r, s, 0.0964200441f);
    r = fmaf(r, s, -0.1390853351f);
    r = fmaf(r, s, 0.1994653599f);
    r = fmaf(r, s, -0.3332985605f);
    r = fmaf(r, s, 0.9999993329f);
    r = r * t;
    if (ay > ax) r = PI_2 - r;
    if (x < 0.f) r = PI - r;
    return copysignf(r, y);
}

// det = a.(b x c) computed directly so p == vertex gives det = 0, den = 0
// exactly (matches numpy reference; verified absmax == 0.0 in round 3).
__device__ __forceinline__ float solid_angle_atan(
    float v0x, float v0y, float v0z,
    float v1x, float v1y, float v1z,
    float v2x, float v2y, float v2z,
    float px, float py, float pz) {
    float ax = v0x - px, ay = v0y - py, az = v0z - pz;
    float bx = v1x - px, by = v1y - py, bz = v1z - pz;
    float cx = v2x - px, cy = v2y - py, cz = v2z - pz;

    float la = __builtin_amdgcn_sqrtf(fmaf(ax, ax, fmaf(ay, ay, az * az)));
    float lb = __builtin_amdgcn_sqrtf(fmaf(bx, bx, fmaf(by, by, bz * bz)));
    float lc = __builtin_amdgcn_sqrtf(fmaf(cx, cx, fmaf(cy, cy, cz * cz)));

    float crx = by * cz - bz * cy;
    float cry = bz * cx - bx * cz;
    float crz = bx * cy - by * cx;
    float det = ax * crx + ay * cry + az * crz;

    float dab = fmaf(ax, bx, fmaf(ay, by, az * bz));
    float dbc = fmaf(bx, cx, fmaf(by, cy, bz * cz));
    float dca = fmaf(cx, ax, fmaf(cy, ay, cz * az));
    float den = fmaf(la * lb, lc, fmaf(dab, lc, fmaf(dbc, la, dca * lb)));

    return fast_atan2f(det, den);
}

// ---------------------------------------------------------------------------
// Kernel 1: fused band-means + triangle gather.
// grid = B * ceil(F/256) blocks, 256 threads. Each block (single b) first
// computes the two band means redundantly (wave0 -> band0, wave1 -> band1),
// then gathers one face per thread into a 16-float record:
//   [v0x v0y v0z v1x][v1y v1z v2x v2y][v2z pad pad pad][pad...]
// ---------------------------------------------------------------------------
__global__ void gather_tris_kernel(const float* __restrict__ verts,
                                   const int* __restrict__ b0i,
                                   const int* __restrict__ b1i,
                                   const int* __restrict__ faces,   // [F][3]
                                   float* __restrict__ tri,         // [B][F][16]
                                   int B, int V, int F, int LB, int nfc) {
    int b  = blockIdx.x / nfc;
    int fc = blockIdx.x - b * nfc;
    int tid = threadIdx.x;
    int wid = tid >> 6, lane = tid & 63;

    __shared__ float sband[6];
    if (wid < 2) {
        const int* bi = wid ? b1i : b0i;
        float sx = 0.f, sy = 0.f, sz = 0.f;
        for (int i = lane; i < LB; i += 64) {
            int vi = bi[i];
            const float* q = verts + ((size_t)b * V + vi) * 3;
            sx += q[0]; sy += q[1]; sz += q[2];
        }
#pragma unroll
        for (int off = 32; off; off >>= 1) {
            sx += __shfl_down(sx, off, 64);
            sy += __shfl_down(sy, off, 64);
            sz += __shfl_down(sz, off, 64);
        }
        if (lane == 0) {
            float inv = 1.0f / (float)LB;
            sband[wid * 3 + 0] = sx * inv;
            sband[wid * 3 + 1] = sy * inv;
            sband[wid * 3 + 2] = sz * inv;
        }
    }
    __syncthreads();

    int f = fc * 256 + tid;
    if (f >= F) return;
    float v[3][3];
#pragma unroll
    for (int k = 0; k < 3; ++k) {
        int vi = faces[f * 3 + k];
        if (vi < V) {
            const float* s = verts + ((size_t)b * V + vi) * 3;
            v[k][0] = s[0]; v[k][1] = s[1]; v[k][2] = s[2];
        } else {
            int j = (vi - V) * 3;
            v[k][0] = sband[j + 0]; v[k][1] = sband[j + 1]; v[k][2] = sband[j + 2];
        }
    }
    float4* d = (float4*)(tri + ((size_t)b * F + f) * 16);
    d[0] = make_float4(v[0][0], v[0][1], v[0][2], v[1][0]);
    d[1] = make_float4(v[1][1], v[1][2], v[2][0], v[2][1]);
    d[2] = make_float4(v[2][2], 0.f, 0.f, 0.f);
    d[3] = make_float4(0.f, 0.f, 0.f, 0.f);
}

// ---------------------------------------------------------------------------
// Kernel 2 (main): broadcast-face winding. grid = B * NF blocks, 256 threads.
// Block (b, s) handles face slice [s*FPB, s*FPB+FPB) against ALL P points.
// Face addresses are wave-uniform -> scalar loads; each thread owns PPB
// points exclusively (no cross-lane reduction). Partials -> ws.
// ---------------------------------------------------------------------------
__global__ __launch_bounds__(256) void winding_bcast_kernel(
    const float* __restrict__ tri,     // [B][F][16]
    const float* __restrict__ verts,   // [B][V][3]
    const int* __restrict__ vidx,      // [P]
    float* __restrict__ partial,       // [NF][B][P]
    int P, int F, int V, int B, int NF) {
    int b = blockIdx.x / NF;
    int s = blockIdx.x - b * NF;
    int f0 = s * FPB;
    int tid = threadIdx.x;

    float px[PPB], py[PPB], pz[PPB], acc[PPB];
#pragma unroll
    for (int j = 0; j < PPB; ++j) {
        int p = j * 256 + tid;
        int pc = (p < P) ? p : (P - 1);
        const float* pt = verts + ((size_t)b * V + vidx[pc]) * 3;
        px[j] = pt[0]; py[j] = pt[1]; pz[j] = pt[2];
        acc[j] = 0.f;
    }

    const float* tb = tri + (size_t)b * F * 16;
#pragma unroll
    for (int i = 0; i < FPB; ++i) {
        int f = f0 + i;
        if (f < F) {
            const float* r = tb + (size_t)f * 16;   // uniform address -> SGPRs
            float v0x = r[0], v0y = r[1], v0z = r[2];
            float v1x = r[3], v1y = r[4], v1z = r[5];
            float v2x = r[6], v2y = r[7], v2z = r[8];
#pragma unroll
            for (int j = 0; j < PPB; ++j) {
                acc[j] += solid_angle_atan(v0x, v0y, v0z, v1x, v1y, v1z,
                                           v2x, v2y, v2z, px[j], py[j], pz[j]);
            }
        }
    }

    float* dst = partial + ((size_t)s * B + b) * P;
#pragma unroll
    for (int j = 0; j < PPB; ++j) {
        int p = j * 256 + tid;
        if (p < P) dst[p] = acc[j];
    }
}

// ---------------------------------------------------------------------------
// Kernel 3: reduce partials over NF slices. idx over B*P; stride B*P floats
// between slices -> coalesced.
// ---------------------------------------------------------------------------
__global__ void reduce_kernel(const float* __restrict__ partial,
                              float* __restrict__ out, int BP, int NF) {
    int idx = blockIdx.x * blockDim.x + threadIdx.x;
    if (idx >= BP) return;
    const float* p = partial + idx;
    float a0 = 0.f, a1 = 0.f, a2 = 0.f, a3 = 0.f;
    int s = 0;
    for (; s + 4 <= NF; s += 4) {
        a0 += p[(size_t)(s + 0) * BP];
        a1 += p[(size_t)(s + 1) * BP];
        a2 += p[(size_t)(s + 2) * BP];
        a3 += p[(size_t)(s + 3) * BP];
    }
    for (; s < NF; ++s) a0 += p[(size_t)s * BP];
    out[idx] = ((a0 + a1) + (a2 + a3)) * INV_TWO_PI;
}

// ---------------------------------------------------------------------------
// Fallback (ws too small): bands in ws head; 1 point per block, gather on fly.
// ---------------------------------------------------------------------------
__global__ void band_means_kernel(const float* __restrict__ verts,
                                  const int* __restrict__ b0i,
                                  const int* __restrict__ b1i,
                                  float* __restrict__ bands,
                                  int V, int LB) {
    int b = blockIdx.x;
    int t = threadIdx.x;
    float s[6] = {0.f, 0.f, 0.f, 0.f, 0.f, 0.f};
    for (int i = t; i < LB; i += 64) {
        int i0 = b0i[i];
        int i1 = b1i[i];
        const float* p0 = verts + ((size_t)b * V + i0) * 3;
        const float* p1 = verts + ((size_t)b * V + i1) * 3;
        s[0] += p0[0]; s[1] += p0[1]; s[2] += p0[2];
        s[3] += p1[0]; s[4] += p1[1]; s[5] += p1[2];
    }
#pragma unroll
    for (int off = 32; off; off >>= 1) {
#pragma unroll
        for (int c = 0; c < 6; ++c) s[c] += __shfl_down(s[c], off, 64);
    }
    if (t == 0) {
        float inv = 1.0f / (float)LB;
#pragma unroll
        for (int c = 0; c < 6; ++c) bands[b * 6 + c] = s[c] * inv;
    }
}

__global__ __launch_bounds__(256) void winding_fallback_kernel(
    const float* __restrict__ verts,
    const int* __restrict__ vidx,
    const int* __restrict__ faces,
    const float* __restrict__ bands,
    float* __restrict__ out,
    int P, int F, int V) {
    int blk = blockIdx.x;
    int b = blk / P;
    int p = blk - b * P;
    int tid = threadIdx.x;

    const float* pt = verts + ((size_t)b * V + vidx[p]) * 3;
    float px = pt[0], py = pt[1], pz = pt[2];
    float b0x = bands[b * 6 + 0], b0y = bands[b * 6 + 1], b0z = bands[b * 6 + 2];
    float b1x = bands[b * 6 + 3], b1y = bands[b * 6 + 4], b1z = bands[b * 6 + 5];

    float acc = 0.f;
    for (int f = tid; f < F; f += 256) {
        float vv[3][3];
#pragma unroll
        for (int k = 0; k < 3; ++k) {
            int vi = faces[f * 3 + k];
            if (vi < V) {
                const float* s = verts + ((size_t)b * V + vi) * 3;
                vv[k][0] = s[0]; vv[k][1] = s[1]; vv[k][2] = s[2];
            } else if (vi == V) {
                vv[k][0] = b0x; vv[k][1] = b0y; vv[k][2] = b0z;
            } else {
                vv[k][0] = b1x; vv[k][1] = b1y; vv[k][2] = b1z;
            }
        }
        acc += solid_angle_atan(vv[0][0], vv[0][1], vv[0][2],
                                vv[1][0], vv[1][1], vv[1][2],
                                vv[2][0], vv[2][1], vv[2][2],
                                px, py, pz);
    }
#pragma unroll
    for (int off = 32; off; off >>= 1) acc += __shfl_down(acc, off, 64);
    __shared__ float part[4];
    int wid = tid >> 6;
    if ((tid & 63) == 0) part[wid] = acc;
    __syncthreads();
    if (tid == 0) {
        out[(size_t)b * P + p] = (part[0] + part[1] + part[2] + part[3]) * INV_TWO_PI;
    }
}

extern "C" void kernel_launch(void* const* d_in, const int* in_sizes, int n_in,
                              void* d_out, int out_size, void* d_ws, size_t ws_size,
                              hipStream_t stream) {
    const float* verts = (const float*)d_in[0];
    const int* svidx   = (const int*)d_in[1];
    const int* b0i     = (const int*)d_in[2];
    const int* b1i     = (const int*)d_in[3];
    const int* faces   = (const int*)d_in[4];
    float* out = (float*)d_out;

    int P  = in_sizes[1];
    int LB = in_sizes[2];
    int F  = in_sizes[4] / 3;
    int B  = out_size / P;
    int V  = in_sizes[0] / (3 * B);

    int NF = (F + FPB - 1) / FPB;          // face slices
    int pts_per_block = 256 * PPB;

    size_t tri_bytes  = (size_t)B * F * 16 * sizeof(float);
    size_t tri_pad    = (tri_bytes + 255) & ~(size_t)255;
    size_t part_bytes = (size_t)NF * B * P * sizeof(float);
    bool use_bcast = (P <= pts_per_block) && (ws_size >= tri_pad + part_bytes);

    if (use_bcast) {
        float* tri     = (float*)d_ws;
        float* partial = (float*)((char*)d_ws + tri_pad);
        int nfc = (F + 255) / 256;
        gather_tris_kernel<<<B * nfc, 256, 0, stream>>>(verts, b0i, b1i, faces,
                                                        tri, B, V, F, LB, nfc);
        winding_bcast_kernel<<<B * NF, 256, 0, stream>>>(tri, verts, svidx,
                                                         partial, P, F, V, B, NF);
        int BP = B * P;
        reduce_kernel<<<(BP + 255) / 256, 256, 0, stream>>>(partial, out, BP, NF);
    } else {
        float* bands = (float*)d_ws;
        band_means_kernel<<<B, 64, 0, stream>>>(verts, b0i, b1i, bands, V, LB);
        winding_fallback_kernel<<<B * P, 256, 0, stream>>>(verts, svidx, faces,
                                                           bands, out, P, F, V);
    }
}

// Round 6
// 82.375 us; speedup vs baseline: 1.2330x; 1.2330x over previous
//
#include <hip/hip_runtime.h>
#include <math.h>

#define INV_TWO_PI 0.15915494309189535f
#define PPB 4  // points per block in the main kernel

// ---------------------------------------------------------------------------
// fast atan2: degree-15 odd minimax on [0,1] + quadrant fixup.
// Branch-cut semantics match numpy: atan2(+-0, neg) = +-pi, atan2(0,0)=0.
// ---------------------------------------------------------------------------
__device__ __forceinline__ float fast_atan2f(float y, float x) {
    const float PI   = 3.14159265358979f;
    const float PI_2 = 1.57079632679490f;
    float ax = fabsf(x), ay = fabsf(y);
    float mx = fmaxf(ax, ay), mn = fminf(ax, ay);
    float inv = __builtin_amdgcn_rcpf(mx);
    float t = (mx > 0.f) ? mn * inv : 0.f;   // guard 0/0
    float s = t * t;
    float r = -0.0040540580f;
    r = fmaf(r, s, 0.0218612288f);
    r = fmaf(r, s, -0.0559098861f);
    r = fmaf(r, s, 0.0964200441f);
    r = fmaf(r, s, -0.1390853351f);
    r = fmaf(r, s, 0.1994653599f);
    r = fmaf(r, s, -0.3332985605f);
    r = fmaf(r, s, 0.9999993329f);
    r = r * t;
    if (ay > ax) r = PI_2 - r;
    if (x < 0.f) r = PI - r;
    return copysignf(r, y);
}

// det = a.(b x c) computed directly so p == vertex gives det = 0, den = 0
// exactly (matches numpy reference; verified absmax == 0.0 in round 3).
__device__ __forceinline__ float solid_angle_atan(
    float v0x, float v0y, float v0z,
    float v1x, float v1y, float v1z,
    float v2x, float v2y, float v2z,
    float px, float py, float pz) {
    float ax = v0x - px, ay = v0y - py, az = v0z - pz;
    float bx = v1x - px, by = v1y - py, bz = v1z - pz;
    float cx = v2x - px, cy = v2y - py, cz = v2z - pz;

    float la = __builtin_amdgcn_sqrtf(fmaf(ax, ax, fmaf(ay, ay, az * az)));
    float lb = __builtin_amdgcn_sqrtf(fmaf(bx, bx, fmaf(by, by, bz * bz)));
    float lc = __builtin_amdgcn_sqrtf(fmaf(cx, cx, fmaf(cy, cy, cz * cz)));

    float crx = by * cz - bz * cy;
    float cry = bz * cx - bx * cz;
    float crz = bx * cy - by * cx;
    float det = ax * crx + ay * cry + az * crz;

    float dab = fmaf(ax, bx, fmaf(ay, by, az * bz));
    float dbc = fmaf(bx, cx, fmaf(by, cy, bz * cz));
    float dca = fmaf(cx, ax, fmaf(cy, ay, cz * az));
    float den = fmaf(la * lb, lc, fmaf(dab, lc, fmaf(dbc, la, dca * lb)));

    return fast_atan2f(det, den);
}

// ---------------------------------------------------------------------------
// Kernel 1: fused band-means + triangle gather (saves one dispatch vs v2).
// grid = B * ceil(F/256), 256 threads. Waves 0/1 redundantly compute the two
// band means (64 verts each) into LDS, then each thread gathers one face into
// a 12-float record: [v0x v0y v0z v1x][v1y v1z v2x v2y][v2z pad pad pad].
// ---------------------------------------------------------------------------
__global__ void gather_tris_kernel(const float* __restrict__ verts,
                                   const int* __restrict__ b0i,
                                   const int* __restrict__ b1i,
                                   const int* __restrict__ faces,   // [F][3]
                                   float* __restrict__ tri,         // [B][F][12]
                                   int B, int V, int F, int LB, int nfc) {
    int b  = blockIdx.x / nfc;
    int fc = blockIdx.x - b * nfc;
    int tid = threadIdx.x;
    int wid = tid >> 6, lane = tid & 63;

    __shared__ float sband[6];
    if (wid < 2) {
        const int* bi = wid ? b1i : b0i;
        float sx = 0.f, sy = 0.f, sz = 0.f;
        for (int i = lane; i < LB; i += 64) {
            int vi = bi[i];
            const float* q = verts + ((size_t)b * V + vi) * 3;
            sx += q[0]; sy += q[1]; sz += q[2];
        }
#pragma unroll
        for (int off = 32; off; off >>= 1) {
            sx += __shfl_down(sx, off, 64);
            sy += __shfl_down(sy, off, 64);
            sz += __shfl_down(sz, off, 64);
        }
        if (lane == 0) {
            float inv = 1.0f / (float)LB;
            sband[wid * 3 + 0] = sx * inv;
            sband[wid * 3 + 1] = sy * inv;
            sband[wid * 3 + 2] = sz * inv;
        }
    }
    __syncthreads();

    int f = fc * 256 + tid;
    if (f >= F) return;
    float v[3][3];
#pragma unroll
    for (int k = 0; k < 3; ++k) {
        int vi = faces[f * 3 + k];
        if (vi < V) {
            const float* s = verts + ((size_t)b * V + vi) * 3;
            v[k][0] = s[0]; v[k][1] = s[1]; v[k][2] = s[2];
        } else {
            int j = (vi - V) * 3;
            v[k][0] = sband[j + 0]; v[k][1] = sband[j + 1]; v[k][2] = sband[j + 2];
        }
    }
    float4* d = (float4*)(tri + ((size_t)b * F + f) * 12);
    d[0] = make_float4(v[0][0], v[0][1], v[0][2], v[1][0]);
    d[1] = make_float4(v[1][1], v[1][2], v[2][0], v[2][1]);
    d[2] = make_float4(v[2][2], 0.f, 0.f, 0.f);
}

// ---------------------------------------------------------------------------
// Kernel 2 (main): PPB points per 256-thread block; threads stride faces.
// Software-pipelined: prefetch face f+256's three float4 into registers
// BEFORE computing face f, so ~700 cycles of VALU cover each L2 load.
// ---------------------------------------------------------------------------
__global__ __launch_bounds__(256) void winding4_kernel(
    const float* __restrict__ tri,    // [B][F][12]
    const float* __restrict__ verts,  // [B][V][3]
    const int* __restrict__ vidx,     // [P]
    float* __restrict__ out,          // [B][P]
    int P, int F, int V) {
    int nPB = (P + PPB - 1) / PPB;
    int b  = blockIdx.x / nPB;
    int pb = blockIdx.x - b * nPB;
    int p0 = pb * PPB;
    int tid = threadIdx.x;

    const float4* tb = (const float4*)(tri + (size_t)b * F * 12);

    // initial face load (f = tid < 256 <= F for our shapes; guarded anyway)
    int f = tid;
    float4 q0 = make_float4(0.f, 0.f, 0.f, 0.f), q1 = q0, q2 = q0;
    if (f < F) {
        q0 = tb[(size_t)f * 3 + 0];
        q1 = tb[(size_t)f * 3 + 1];
        q2 = tb[(size_t)f * 3 + 2];
    }

    float px[PPB], py[PPB], pz[PPB], acc[PPB];
#pragma unroll
    for (int j = 0; j < PPB; ++j) {
        int p = (p0 + j < P) ? (p0 + j) : (P - 1);
        const float* pt = verts + ((size_t)b * V + vidx[p]) * 3;
        px[j] = pt[0]; py[j] = pt[1]; pz[j] = pt[2];
        acc[j] = 0.f;
    }

    while (f < F) {
        // prefetch next face before computing current
        int fn = f + 256;
        float4 n0 = q0, n1 = q1, n2 = q2;
        if (fn < F) {
            n0 = tb[(size_t)fn * 3 + 0];
            n1 = tb[(size_t)fn * 3 + 1];
            n2 = tb[(size_t)fn * 3 + 2];
        }
#pragma unroll
        for (int j = 0; j < PPB; ++j) {
            acc[j] += solid_angle_atan(q0.x, q0.y, q0.z,
                                       q0.w, q1.x, q1.y,
                                       q1.z, q1.w, q2.x,
                                       px[j], py[j], pz[j]);
        }
        q0 = n0; q1 = n1; q2 = n2;
        f = fn;
    }

#pragma unroll
    for (int off = 32; off; off >>= 1) {
#pragma unroll
        for (int j = 0; j < PPB; ++j) acc[j] += __shfl_down(acc[j], off, 64);
    }

    __shared__ float part[4][PPB];
    int wid = tid >> 6;
    if ((tid & 63) == 0) {
#pragma unroll
        for (int j = 0; j < PPB; ++j) part[wid][j] = acc[j];
    }
    __syncthreads();
    if (tid < PPB) {
        int p = p0 + tid;
        if (p < P) {
            float tot = part[0][tid] + part[1][tid] + part[2][tid] + part[3][tid];
            out[(size_t)b * P + p] = tot * INV_TWO_PI;
        }
    }
}

// ---------------------------------------------------------------------------
// Fallback (ws too small): bands in ws head; 1 point per block, gather on fly.
// ---------------------------------------------------------------------------
__global__ void band_means_kernel(const float* __restrict__ verts,
                                  const int* __restrict__ b0i,
                                  const int* __restrict__ b1i,
                                  float* __restrict__ bands,
                                  int V, int LB) {
    int b = blockIdx.x;
    int t = threadIdx.x;
    float s[6] = {0.f, 0.f, 0.f, 0.f, 0.f, 0.f};
    for (int i = t; i < LB; i += 64) {
        int i0 = b0i[i];
        int i1 = b1i[i];
        const float* p0 = verts + ((size_t)b * V + i0) * 3;
        const float* p1 = verts + ((size_t)b * V + i1) * 3;
        s[0] += p0[0]; s[1] += p0[1]; s[2] += p0[2];
        s[3] += p1[0]; s[4] += p1[1]; s[5] += p1[2];
    }
#pragma unroll
    for (int off = 32; off; off >>= 1) {
#pragma unroll
        for (int c = 0; c < 6; ++c) s[c] += __shfl_down(s[c], off, 64);
    }
    if (t == 0) {
        float inv = 1.0f / (float)LB;
#pragma unroll
        for (int c = 0; c < 6; ++c) bands[b * 6 + c] = s[c] * inv;
    }
}

__global__ __launch_bounds__(256) void winding_fallback_kernel(
    const float* __restrict__ verts,
    const int* __restrict__ vidx,
    const int* __restrict__ faces,
    const float* __restrict__ bands,
    float* __restrict__ out,
    int P, int F, int V) {
    int blk = blockIdx.x;
    int b = blk / P;
    int p = blk - b * P;
    int tid = threadIdx.x;

    const float* pt = verts + ((size_t)b * V + vidx[p]) * 3;
    float px = pt[0], py = pt[1], pz = pt[2];
    float b0x = bands[b * 6 + 0], b0y = bands[b * 6 + 1], b0z = bands[b * 6 + 2];
    float b1x = bands[b * 6 + 3], b1y = bands[b * 6 + 4], b1z = bands[b * 6 + 5];

    float acc = 0.f;
    for (int f = tid; f < F; f += 256) {
        float vv[3][3];
#pragma unroll
        for (int k = 0; k < 3; ++k) {
            int vi = faces[f * 3 + k];
            if (vi < V) {
                const float* s = verts + ((size_t)b * V + vi) * 3;
                vv[k][0] = s[0]; vv[k][1] = s[1]; vv[k][2] = s[2];
            } else if (vi == V) {
                vv[k][0] = b0x; vv[k][1] = b0y; vv[k][2] = b0z;
            } else {
                vv[k][0] = b1x; vv[k][1] = b1y; vv[k][2] = b1z;
            }
        }
        acc += solid_angle_atan(vv[0][0], vv[0][1], vv[0][2],
                                vv[1][0], vv[1][1], vv[1][2],
                                vv[2][0], vv[2][1], vv[2][2],
                                px, py, pz);
    }
#pragma unroll
    for (int off = 32; off; off >>= 1) acc += __shfl_down(acc, off, 64);
    __shared__ float part[4];
    int wid = tid >> 6;
    if ((tid & 63) == 0) part[wid] = acc;
    __syncthreads();
    if (tid == 0) {
        out[(size_t)b * P + p] = (part[0] + part[1] + part[2] + part[3]) * INV_TWO_PI;
    }
}

extern "C" void kernel_launch(void* const* d_in, const int* in_sizes, int n_in,
                              void* d_out, int out_size, void* d_ws, size_t ws_size,
                              hipStream_t stream) {
    const float* verts = (const float*)d_in[0];
    const int* svidx   = (const int*)d_in[1];
    const int* b0i     = (const int*)d_in[2];
    const int* b1i     = (const int*)d_in[3];
    const int* faces   = (const int*)d_in[4];
    float* out = (float*)d_out;

    int P  = in_sizes[1];
    int LB = in_sizes[2];
    int F  = in_sizes[4] / 3;
    int B  = out_size / P;
    int V  = in_sizes[0] / (3 * B);

    size_t tri_bytes = (size_t)B * F * 12 * sizeof(float);
    bool use_prep = (ws_size >= tri_bytes);

    if (use_prep) {
        float* tri = (float*)d_ws;
        int nfc = (F + 255) / 256;
        gather_tris_kernel<<<B * nfc, 256, 0, stream>>>(verts, b0i, b1i, faces,
                                                        tri, B, V, F, LB, nfc);
        int nPB = (P + PPB - 1) / PPB;
        winding4_kernel<<<B * nPB, 256, 0, stream>>>(tri, verts, svidx, out, P, F, V);
    } else {
        float* bands = (float*)d_ws;
        band_means_kernel<<<B, 64, 0, stream>>>(verts, b0i, b1i, bands, V, LB);
        winding_fallback_kernel<<<B * P, 256, 0, stream>>>(verts, svidx, faces,
                                                           bands, out, P, F, V);
    }
}